// Round 2
// baseline (539.563 us; speedup 1.0000x reference)
//
#include <hip/hip_runtime.h>

// SoftPool2d: x (16, 96, 256, 256) f32, 2x2 window, stride 2, no pad.
// out (16, 96, 128, 128) f32. out[p] = sum(t_i * softmax(t)_i) over 4 taps.
//
// Streaming, memory-bound. Ideal traffic: 402.7 MB read + 100.7 MB write
// = 503 MB -> ~85 us at the 6.3 TB/s achievable ceiling.
//
// A/B this round: PLAIN cached loads instead of __builtin_nontemporal_load.
// Every kernel variant benched so far (incl. the prior session's) used nt
// loads; all landed at an identical dur_us. nt loads set the no-allocate
// bits on the global encoding and are the one untested common factor. The
// 6.29 TB/s copy ceiling (m13) was measured with plain loads. Stores stay
// nontemporal: output is write-once/never-read, so skipping write-allocate
// avoids polluting L2/MALL with 100 MB of dead lines.
//
// Layout (unchanged from round 1): every load is unit-stride across lanes --
// lane i reads the f32x4 at col 4*i, so one global_load_dwordx4 covers a
// full contiguous 1 KB input row per wave with 100% line utilization.
// Each thread: 4 input rows x 4 cols (4x 16 B loads in flight)
//              -> 2x2 output pixels (2x 8 B coalesced nt stores).

#define H_IN   256
#define W_IN   256
#define H_OUT  128
#define W_OUT  128

typedef float f32x4 __attribute__((ext_vector_type(4)));
typedef float f32x2 __attribute__((ext_vector_type(2)));

__device__ __forceinline__ float softpool4(float a, float b, float c, float d) {
    float m  = fmaxf(fmaxf(a, b), fmaxf(c, d));
    float ea = __expf(a - m);
    float eb = __expf(b - m);
    float ec = __expf(c - m);
    float ed = __expf(d - m);
    float num = a * ea + b * eb + c * ec + d * ed;
    float den = (ea + eb) + (ec + ed);
    return num * __builtin_amdgcn_rcpf(den);
}

__global__ __launch_bounds__(256)
void SoftPool2d_850403524762_kernel(const float* __restrict__ x,
                                    float* __restrict__ out,
                                    int n_threads) {
    int tid = blockIdx.x * blockDim.x + threadIdx.x;
    if (tid >= n_threads) return;

    // Wave-level layout: all 64 lanes of a wave share r2; c4 = lane id.
    int c4 = tid & 63;             // column quad: input cols 4*c4 .. 4*c4+3
    int r2 = tid >> 6;             // output row-pair id
    int hp = r2 & (H_OUT / 2 - 1); // row pair within image (H_OUT/2 = 64)
    int bc = r2 >> 6;              // flattened (b*c)

    const float* p = x + (size_t)bc * (H_IN * W_IN)
                       + (size_t)(4 * hp) * W_IN
                       + 4 * c4;

    // 4 input rows, one unit-stride 16 B PLAIN load each (4 in flight).
    const f32x4 t0 = *(const f32x4*)(p);
    const f32x4 b0 = *(const f32x4*)(p + W_IN);
    const f32x4 t1 = *(const f32x4*)(p + 2 * W_IN);
    const f32x4 b1 = *(const f32x4*)(p + 3 * W_IN);

    // Each f32x4 holds two complete horizontal window-pairs (cols are even-
    // aligned), so both 2x2 windows per row-pair are lane-local.
    f32x2 o0, o1;
    o0.x = softpool4(t0.x, t0.y, b0.x, b0.y);
    o0.y = softpool4(t0.z, t0.w, b0.z, b0.w);
    o1.x = softpool4(t1.x, t1.y, b1.x, b1.y);
    o1.y = softpool4(t1.z, t1.w, b1.z, b1.w);

    float* op = out + (size_t)bc * (H_OUT * W_OUT)
                    + (size_t)(2 * hp) * W_OUT
                    + 2 * c4;
    __builtin_nontemporal_store(o0, (f32x2*)op);           // output row 2*hp
    __builtin_nontemporal_store(o1, (f32x2*)(op + W_OUT)); // output row 2*hp+1
}

extern "C" void kernel_launch(void* const* d_in, const int* in_sizes, int n_in,
                              void* d_out, int out_size, void* d_ws, size_t ws_size,
                              hipStream_t stream) {
    const float* x  = (const float*)d_in[0];
    float* out      = (float*)d_out;

    // One thread per 2x2 output patch: 16 * 96 * (128/2) * (128/2) threads
    const int n_threads = 16 * 96 * (H_OUT / 2) * (W_OUT / 2); // 6,291,456
    const int block     = 256;
    const int grid      = (n_threads + block - 1) / block;     // 24,576

    SoftPool2d_850403524762_kernel<<<grid, block, 0, stream>>>(x, out, n_threads);
}

// Round 3
// 526.229 us; speedup vs baseline: 1.0253x; 1.0253x over previous
//
#include <hip/hip_runtime.h>

// SoftPool2d: x (16, 96, 256, 256) f32, 2x2 window, stride 2, no pad.
// out (16, 96, 128, 128) f32. out[p] = sum(t_i * softmax(t)_i) over 4 taps.
//
// Streaming, memory-bound. Ideal traffic: 402.7 MB read + 100.7 MB write
// = 503 MB -> ~85 us at the ~6 TB/s achievable mixed-stream ceiling.
//
// Round-2 post-mortem: plain cached loads REGRESSED +23 us -> nt loads are
// a win (no-allocate avoids L2/LLC pollution on a read-once stream); revert.
// Also proves kernel deltas show 1:1 in dur_us.
//
// This round: persistent grid + grid-stride loop. Two different one-shot
// layouts (round 0/1) were identical to 35 ns -> if the kernel is NOT at
// the HBM floor, the bound is layout-invariant per-block overhead / load
// issue latency from 24,576 short-lived blocks. 2048 blocks (8/CU) x 12
// tiles/thread, unroll 2, keeps ~8 nt loads in flight per thread and
// amortizes launch + address setup. If this is null too, the kernel is at
// its floor (ROOFLINE).
//
// Layout per tile (unchanged, best known): lane i reads the f32x4 at col
// 4*i -> one global_load_dwordx4 covers a contiguous 1 KB input row per
// wave; a wave's 4 loads cover 4 CONSECUTIVE rows = contiguous 4 KB read;
// stores are a contiguous 1 KB per wave. 100% line utilization everywhere.

#define H_IN   256
#define W_IN   256
#define H_OUT  128
#define W_OUT  128

typedef float f32x4 __attribute__((ext_vector_type(4)));
typedef float f32x2 __attribute__((ext_vector_type(2)));

__device__ __forceinline__ float softpool4(float a, float b, float c, float d) {
    float m  = fmaxf(fmaxf(a, b), fmaxf(c, d));
    float ea = __expf(a - m);
    float eb = __expf(b - m);
    float ec = __expf(c - m);
    float ed = __expf(d - m);
    float num = a * ea + b * eb + c * ec + d * ed;
    float den = (ea + eb) + (ec + ed);
    return num * __builtin_amdgcn_rcpf(den);
}

__global__ __launch_bounds__(256)
void SoftPool2d_850403524762_kernel(const float* __restrict__ x,
                                    float* __restrict__ out,
                                    int n_tiles) {
    const int tid0   = blockIdx.x * blockDim.x + threadIdx.x;
    const int stride = gridDim.x * blockDim.x;   // 524,288 -> exactly 12 iters

    #pragma unroll 2
    for (int tid = tid0; tid < n_tiles; tid += stride) {
        // Wave-level layout: all 64 lanes of a wave share r2; c4 = lane id.
        int c4 = tid & 63;             // column quad: input cols 4*c4..4*c4+3
        int r2 = tid >> 6;             // output row-pair id
        int hp = r2 & (H_OUT / 2 - 1); // row pair within image (64 pairs)
        int bc = r2 >> 6;              // flattened (b*c)

        const float* p = x + (size_t)bc * (H_IN * W_IN)
                           + (size_t)(4 * hp) * W_IN
                           + 4 * c4;

        // 4 input rows, one unit-stride 16 B nt load each (4+ in flight)
        const f32x4 t0 = __builtin_nontemporal_load((const f32x4*)(p));
        const f32x4 b0 = __builtin_nontemporal_load((const f32x4*)(p + W_IN));
        const f32x4 t1 = __builtin_nontemporal_load((const f32x4*)(p + 2 * W_IN));
        const f32x4 b1 = __builtin_nontemporal_load((const f32x4*)(p + 3 * W_IN));

        // Each f32x4 holds two complete horizontal window-pairs (cols are
        // even-aligned), so both 2x2 windows per row-pair are lane-local.
        f32x2 o0, o1;
        o0.x = softpool4(t0.x, t0.y, b0.x, b0.y);
        o0.y = softpool4(t0.z, t0.w, b0.z, b0.w);
        o1.x = softpool4(t1.x, t1.y, b1.x, b1.y);
        o1.y = softpool4(t1.z, t1.w, b1.z, b1.w);

        float* op = out + (size_t)bc * (H_OUT * W_OUT)
                        + (size_t)(2 * hp) * W_OUT
                        + 2 * c4;
        __builtin_nontemporal_store(o0, (f32x2*)op);           // row 2*hp
        __builtin_nontemporal_store(o1, (f32x2*)(op + W_OUT)); // row 2*hp+1
    }
}

extern "C" void kernel_launch(void* const* d_in, const int* in_sizes, int n_in,
                              void* d_out, int out_size, void* d_ws, size_t ws_size,
                              hipStream_t stream) {
    const float* x  = (const float*)d_in[0];
    float* out      = (float*)d_out;

    // One tile per 2x2 output patch: 16 * 96 * 64 * 64 tiles
    const int n_tiles = 16 * 96 * (H_OUT / 2) * (W_OUT / 2); // 6,291,456
    const int block   = 256;
    const int grid    = 2048;  // 8 blocks/CU, persistent; 12 tiles/thread

    SoftPool2d_850403524762_kernel<<<grid, block, 0, stream>>>(x, out, n_tiles);
}

// Round 4
// 518.243 us; speedup vs baseline: 1.0411x; 1.0154x over previous
//
#include <hip/hip_runtime.h>

// SoftPool2d: x (16, 96, 256, 256) f32, 2x2 window, stride 2, no pad.
// out (16, 96, 128, 128) f32. out[p] = sum(t_i * softmax(t)_i) over 4 taps.
//
// FINAL (revert to round-1 best). Streaming, memory-bound, single pass:
// 402.7 MB read + 100.7 MB write. Session A/B ledger:
//   - unit-stride nt loads (this)            : 516.68 us  <- best
//   - strided-pair nt loads (prev session)   : 516.72 us  (null delta)
//   - plain cached loads                     : 539.56 us  (+23: L2/LLC
//     pollution on a read-once 403 MB stream; nt no-allocate wins)
//   - persistent grid, 12 tiles/thread       : 526.23 us  (+9.5: loop
//     overhead with zero launch-bound benefit)
// Kernel never ranks in rocprof top-5 (all ~250 us poison fills at 6.4
// TB/s) -> kernel < 245 us; layout-invariance + regression-sensitivity
// imply it sits at the HBM traffic floor (~85-95 us), remainder of
// dur_us is fixed harness fill/restore work inside the timed region.
//
// Layout: lane i reads the f32x4 at col 4*i -> one global_load_dwordx4
// covers a contiguous 1 KB input row per wave (100% line utilization);
// a thread's 4 loads cover 4 consecutive rows (wave reads contiguous
// 4 KB). Two complete 2x2 windows are lane-local per row pair. Stores:
// two contiguous 512 B nt dwordx2 per wave.

#define H_IN   256
#define W_IN   256
#define H_OUT  128
#define W_OUT  128

typedef float f32x4 __attribute__((ext_vector_type(4)));
typedef float f32x2 __attribute__((ext_vector_type(2)));

__device__ __forceinline__ float softpool4(float a, float b, float c, float d) {
    float m  = fmaxf(fmaxf(a, b), fmaxf(c, d));
    float ea = __expf(a - m);
    float eb = __expf(b - m);
    float ec = __expf(c - m);
    float ed = __expf(d - m);
    float num = a * ea + b * eb + c * ec + d * ed;
    float den = (ea + eb) + (ec + ed);
    return num * __builtin_amdgcn_rcpf(den);
}

__global__ __launch_bounds__(256)
void SoftPool2d_850403524762_kernel(const float* __restrict__ x,
                                    float* __restrict__ out,
                                    int n_threads) {
    int tid = blockIdx.x * blockDim.x + threadIdx.x;
    if (tid >= n_threads) return;

    // Wave-level layout: all 64 lanes of a wave share r2; c4 = lane id.
    int c4 = tid & 63;             // column quad: input cols 4*c4 .. 4*c4+3
    int r2 = tid >> 6;             // output row-pair id
    int hp = r2 & (H_OUT / 2 - 1); // row pair within image (H_OUT/2 = 64)
    int bc = r2 >> 6;              // flattened (b*c)

    const float* p = x + (size_t)bc * (H_IN * W_IN)
                       + (size_t)(4 * hp) * W_IN
                       + 4 * c4;

    // 4 input rows, one unit-stride 16 B nt load each (4 in flight)
    const f32x4 t0 = __builtin_nontemporal_load((const f32x4*)(p));
    const f32x4 b0 = __builtin_nontemporal_load((const f32x4*)(p + W_IN));
    const f32x4 t1 = __builtin_nontemporal_load((const f32x4*)(p + 2 * W_IN));
    const f32x4 b1 = __builtin_nontemporal_load((const f32x4*)(p + 3 * W_IN));

    // Each f32x4 holds two complete horizontal window-pairs (cols are even-
    // aligned), so both 2x2 windows per row-pair are lane-local.
    f32x2 o0, o1;
    o0.x = softpool4(t0.x, t0.y, b0.x, b0.y);
    o0.y = softpool4(t0.z, t0.w, b0.z, b0.w);
    o1.x = softpool4(t1.x, t1.y, b1.x, b1.y);
    o1.y = softpool4(t1.z, t1.w, b1.z, b1.w);

    float* op = out + (size_t)bc * (H_OUT * W_OUT)
                    + (size_t)(2 * hp) * W_OUT
                    + 2 * c4;
    __builtin_nontemporal_store(o0, (f32x2*)op);           // output row 2*hp
    __builtin_nontemporal_store(o1, (f32x2*)(op + W_OUT)); // output row 2*hp+1
}

extern "C" void kernel_launch(void* const* d_in, const int* in_sizes, int n_in,
                              void* d_out, int out_size, void* d_ws, size_t ws_size,
                              hipStream_t stream) {
    const float* x  = (const float*)d_in[0];
    float* out      = (float*)d_out;

    // One thread per 2x2 output patch: 16 * 96 * (128/2) * (128/2) threads
    const int n_threads = 16 * 96 * (H_OUT / 2) * (W_OUT / 2); // 6,291,456
    const int block     = 256;
    const int grid      = (n_threads + block - 1) / block;     // 24,576

    SoftPool2d_850403524762_kernel<<<grid, block, 0, stream>>>(x, out, n_threads);
}